// Round 1
// baseline (181.002 us; speedup 1.0000x reference)
//
#include <hip/hip_runtime.h>
#include <hip/hip_bf16.h>

// MaxPoolingMatching: out[b,l,p] = max_m cos( s1[b,l,:]∘k[p,:], s2[b,m,:]∘k[p,:] )
// B=16, L=256, D=256, P=20.
// Strategy: per (b,p,l-tile-64) block: stage bf16 x1=s1∘k in LDS once, loop m-tiles
// staging bf16 x2, 16x16x32 bf16 MFMA (A=x2 rows=m, B=x1 cols=l -> C[m,l]),
// epilogue scales by rsqrt(max(||x||^2,EPS)) in fp32 and max-reduces over m
// (in-lane regs + shfl_xor(16,32) cross-quad).

#define B_DIM 16
#define L_DIM 256
#define D_DIM 256
#define P_DIM 20
#define TL 64
#define TM 64
#define LDX 264              // 256 + 8 bf16 pad: keeps 16B alignment, breaks bank stride
#define EPS 1e-12f

typedef __attribute__((ext_vector_type(8))) __bf16 bf16x8;
typedef __attribute__((ext_vector_type(4))) float f32x4;

__device__ __forceinline__ unsigned short f2bf(float x) {
  unsigned int u = __float_as_uint(x);
  u += 0x7fffu + ((u >> 16) & 1u);   // round-to-nearest-even
  return (unsigned short)(u >> 16);
}

__global__ __launch_bounds__(256, 2)
void mpm_kernel(const float* __restrict__ s1g, const float* __restrict__ s2g,
                const float* __restrict__ kg, float* __restrict__ outg) {
  __shared__ unsigned short X1[TL * LDX];   // bf16 bits, row-major [l][d]
  __shared__ unsigned short X2[TM * LDX];   // bf16 bits, row-major [m][d]
  __shared__ float kf[D_DIM];
  __shared__ float nsq1[TL];
  __shared__ float nsq2[TM];
  __shared__ float outtmp[2][TL];

  const int tid  = threadIdx.x;
  const int lane = tid & 63;
  const int wave = tid >> 6;      // 0..3
  const int wl   = wave & 1;      // l-half of block tile
  const int wm   = wave >> 1;     // m-half of block tile
  const int lr   = lane & 15;
  const int q    = lane >> 4;

  const int bid = blockIdx.x;
  const int lt = bid & 3;
  const int p  = (bid >> 2) % P_DIM;
  const int b  = bid / (4 * P_DIM);
  const int l0 = lt * TL;

  kf[tid] = kg[p * D_DIM + tid];
  __syncthreads();

  // each lane owns d-range [lane*4, lane*4+4) for all prep rows
  const float4 kv = *(const float4*)&kf[lane * 4];

  // ---- X1 prep: 64 rows, one row per wave per iteration (coalesced 1KB/row) ----
  const float* s1b = s1g + ((size_t)b * L_DIM + l0) * D_DIM;
  #pragma unroll
  for (int i = 0; i < 16; ++i) {
    const int row = i * 4 + wave;
    float4 sv = *(const float4*)(s1b + row * D_DIM + lane * 4);
    float x0 = sv.x * kv.x, x1 = sv.y * kv.y, x2 = sv.z * kv.z, x3 = sv.w * kv.w;
    unsigned int p0 = ((unsigned int)f2bf(x1) << 16) | f2bf(x0);
    unsigned int p1 = ((unsigned int)f2bf(x3) << 16) | f2bf(x2);
    *(uint2*)&X1[row * LDX + lane * 4] = make_uint2(p0, p1);
    float sq = x0 * x0 + x1 * x1 + x2 * x2 + x3 * x3;
    #pragma unroll
    for (int off = 1; off < 64; off <<= 1) sq += __shfl_xor(sq, off);
    if (lane == 0) nsq1[row] = sq;
  }

  float rmax0 = -1e30f, rmax1 = -1e30f;   // running max over m for cols wl*32+lr, +16

  const float* s2b0 = s2g + (size_t)b * L_DIM * D_DIM;

  for (int mt = 0; mt < L_DIM / TM; ++mt) {
    __syncthreads();   // previous iteration's MFMA/epilogue reads done
    // ---- X2 prep ----
    const float* s2b = s2b0 + (size_t)mt * TM * D_DIM;
    #pragma unroll
    for (int i = 0; i < 16; ++i) {
      const int row = i * 4 + wave;
      float4 sv = *(const float4*)(s2b + row * D_DIM + lane * 4);
      float x0 = sv.x * kv.x, x1 = sv.y * kv.y, x2 = sv.z * kv.z, x3 = sv.w * kv.w;
      unsigned int p0 = ((unsigned int)f2bf(x1) << 16) | f2bf(x0);
      unsigned int p1 = ((unsigned int)f2bf(x3) << 16) | f2bf(x2);
      *(uint2*)&X2[row * LDX + lane * 4] = make_uint2(p0, p1);
      float sq = x0 * x0 + x1 * x1 + x2 * x2 + x3 * x3;
      #pragma unroll
      for (int off = 1; off < 64; off <<= 1) sq += __shfl_xor(sq, off);
      if (lane == 0) nsq2[row] = sq;
    }
    __syncthreads();   // staging visible

    // ---- MFMA: wave computes C[32 m x 32 l] over K=256 ----
    f32x4 acc00 = {0,0,0,0}, acc01 = {0,0,0,0}, acc10 = {0,0,0,0}, acc11 = {0,0,0,0};
    const unsigned short* a0p = &X2[(wm * 32 +      lr) * LDX + q * 8];
    const unsigned short* a1p = &X2[(wm * 32 + 16 + lr) * LDX + q * 8];
    const unsigned short* b0p = &X1[(wl * 32 +      lr) * LDX + q * 8];
    const unsigned short* b1p = &X1[(wl * 32 + 16 + lr) * LDX + q * 8];
    #pragma unroll
    for (int kt = 0; kt < 8; ++kt) {
      bf16x8 a0 = *(const bf16x8*)(a0p + kt * 32);
      bf16x8 a1 = *(const bf16x8*)(a1p + kt * 32);
      bf16x8 b0 = *(const bf16x8*)(b0p + kt * 32);
      bf16x8 b1 = *(const bf16x8*)(b1p + kt * 32);
      acc00 = __builtin_amdgcn_mfma_f32_16x16x32_bf16(a0, b0, acc00, 0, 0, 0);
      acc01 = __builtin_amdgcn_mfma_f32_16x16x32_bf16(a0, b1, acc01, 0, 0, 0);
      acc10 = __builtin_amdgcn_mfma_f32_16x16x32_bf16(a1, b0, acc10, 0, 0, 0);
      acc11 = __builtin_amdgcn_mfma_f32_16x16x32_bf16(a1, b1, acc11, 0, 0, 0);
    }

    // ---- epilogue: scale by inv-norms, fold into running max over m ----
    float rl0 = rsqrtf(fmaxf(nsq1[wl * 32 +      lr], EPS));
    float rl1 = rsqrtf(fmaxf(nsq1[wl * 32 + 16 + lr], EPS));
    #pragma unroll
    for (int r = 0; r < 4; ++r) {
      float rm0 = rsqrtf(fmaxf(nsq2[wm * 32 +      q * 4 + r], EPS));
      float rm1 = rsqrtf(fmaxf(nsq2[wm * 32 + 16 + q * 4 + r], EPS));
      // rl > 0, so factoring it outside the max over m-rows is valid
      rmax0 = fmaxf(rmax0, fmaxf(acc00[r] * rm0, acc10[r] * rm1) * rl0);
      rmax1 = fmaxf(rmax1, fmaxf(acc01[r] * rm0, acc11[r] * rm1) * rl1);
    }
  }

  // cross-quad: combine the 4 quads (each lane has max over its own m rows)
  rmax0 = fmaxf(rmax0, __shfl_xor(rmax0, 16));
  rmax0 = fmaxf(rmax0, __shfl_xor(rmax0, 32));
  rmax1 = fmaxf(rmax1, __shfl_xor(rmax1, 16));
  rmax1 = fmaxf(rmax1, __shfl_xor(rmax1, 32));
  if (q == 0) {
    outtmp[wm][wl * 32 + lr]      = rmax0;
    outtmp[wm][wl * 32 + 16 + lr] = rmax1;
  }
  __syncthreads();
  if (tid < TL) {
    float v = fmaxf(outtmp[0][tid], outtmp[1][tid]);
    outg[((size_t)b * L_DIM + (l0 + tid)) * P_DIM + p] = v;
  }
}

extern "C" void kernel_launch(void* const* d_in, const int* in_sizes, int n_in,
                              void* d_out, int out_size, void* d_ws, size_t ws_size,
                              hipStream_t stream) {
  const float* s1 = (const float*)d_in[0];
  const float* s2 = (const float*)d_in[1];
  const float* kg = (const float*)d_in[2];
  float* out = (float*)d_out;
  dim3 grid(B_DIM * P_DIM * (L_DIM / TL));   // 1280 blocks
  mpm_kernel<<<grid, dim3(256), 0, stream>>>(s1, s2, kg, out);
}

// Round 2
// 96.985 us; speedup vs baseline: 1.8663x; 1.8663x over previous
//
#include <hip/hip_runtime.h>
#include <hip/hip_bf16.h>

// MaxPoolingMatching: out[b,l,p] = max_m cos( s1[b,l,:]∘k[p,:], s2[b,m,:]∘k[p,:] )
// B=16, L=256, D=256, P=20.
//
// Algebra: cos numerator = Σ_d (s1 k)(s2 k) = Σ_d (s1 k²)·s2  →  fold k² (and the
// l-side reciprocal norm) into x̂1 = bf16(s1·k²·rn1); the s2 operand is raw bf16(s2),
// p-INDEPENDENT → precomputed once by prep_kernel along with reciprocal norms
// rn = rsqrt(max(Σ s²k², EPS)). Main kernel: X1 prep (64 rows, no reduce chains),
// X2 async-staged via global_load_lds (16B, XOR-swizzled granules to kill bank
// conflicts on A-fragment reads), 16x16x32 bf16 MFMA, epilogue scales by rn2 and
// max-reduces over m in-register + shfl_xor(16,32).

#define B_DIM 16
#define L_DIM 256
#define D_DIM 256
#define P_DIM 20
#define TL 64
#define TM 64
#define LDX 264              // X1 pad: row stride 528B ≡ 4 dwords mod 32 banks → 2-way (free)
#define EPS 1e-12f

typedef __attribute__((ext_vector_type(8))) __bf16 bf16x8;
typedef __attribute__((ext_vector_type(4))) float f32x4;

__device__ __forceinline__ unsigned short f2bf(float x) {
  unsigned int u = __float_as_uint(x);
  u += 0x7fffu + ((u >> 16) & 1u);   // RNE
  return (unsigned short)(u >> 16);
}

// ---------------- prep: reciprocal norms + bf16(s2) ----------------
// one wave per (sentence, b, l) row; 2048 blocks x 256 threads
__global__ __launch_bounds__(256)
void prep_kernel(const float* __restrict__ s1, const float* __restrict__ s2,
                 const float* __restrict__ kg, float* __restrict__ rn1,
                 float* __restrict__ rn2, unsigned short* __restrict__ s2bf) {
  const int lane = threadIdx.x & 63;
  const int gw   = blockIdx.x * 4 + (threadIdx.x >> 6);   // 0..8191
  const int sent = gw >> 12;                               // 0: s1, 1: s2
  const int row  = gw & 4095;                              // b*256 + l
  const float* src = sent ? s2 : s1;
  float4 sv = *(const float4*)(src + (size_t)row * D_DIM + lane * 4);
  if (sent) {
    unsigned int p0 = ((unsigned int)f2bf(sv.y) << 16) | f2bf(sv.x);
    unsigned int p1 = ((unsigned int)f2bf(sv.w) << 16) | f2bf(sv.z);
    *(uint2*)&s2bf[(size_t)row * D_DIM + lane * 4] = make_uint2(p0, p1);
  }
  float q0 = sv.x * sv.x, q1 = sv.y * sv.y, q2 = sv.z * sv.z, q3 = sv.w * sv.w;
  float* rn = sent ? rn2 : rn1;
  const int b = row >> 8, l = row & 255;
  #pragma unroll 4
  for (int p = 0; p < P_DIM; ++p) {
    float4 kv = *(const float4*)(kg + p * D_DIM + lane * 4);
    float v = q0 * kv.x * kv.x + q1 * kv.y * kv.y + q2 * kv.z * kv.z + q3 * kv.w * kv.w;
    #pragma unroll
    for (int off = 1; off < 64; off <<= 1) v += __shfl_xor(v, off);
    if (lane == 0) rn[((size_t)b * P_DIM + p) * L_DIM + l] = rsqrtf(fmaxf(v, EPS));
  }
}

// ---------------- main: batched GEMM + max epilogue ----------------
__global__ __launch_bounds__(256, 2)
void mpm_main(const float* __restrict__ s1, const unsigned short* __restrict__ s2bf,
              const float* __restrict__ kg, const float* __restrict__ rn1,
              const float* __restrict__ rn2, float* __restrict__ outg) {
  __shared__ __align__(16) unsigned short X1[TL * LDX];   // x̂1 = bf16(s1·k²·rn1), padded
  __shared__ __align__(16) unsigned short X2[TM * 256];   // bf16(s2), XOR-swizzled 16B granules
  __shared__ float RN1[TL];
  __shared__ float RN2[L_DIM];
  __shared__ float outtmp[2][TL];

  const int tid  = threadIdx.x;
  const int lane = tid & 63;
  const int wave = tid >> 6;
  const int wl = wave & 1, wm = wave >> 1;
  const int lr = lane & 15, q = lane >> 4;

  const int bid = blockIdx.x;
  const int lt = bid & 3;
  const int p  = (bid >> 2) % P_DIM;
  const int b  = bid / (4 * P_DIM);
  const int l0 = lt * TL;

  // reciprocal norms -> LDS
  if (tid < TL) RN1[tid] = rn1[((size_t)b * P_DIM + p) * L_DIM + l0 + tid];
  RN2[tid] = rn2[((size_t)b * P_DIM + p) * L_DIM + tid];
  __syncthreads();

  // k² for this p (each lane owns 4 d's)
  float4 kv = *(const float4*)(kg + p * D_DIM + lane * 4);
  const float k0 = kv.x * kv.x, k1 = kv.y * kv.y, k2 = kv.z * kv.z, k3 = kv.w * kv.w;

  // X1 prep: one row per wave per iter, coalesced 1KB row loads
  const float* s1b = s1 + ((size_t)b * L_DIM + l0) * D_DIM;
  #pragma unroll
  for (int i = 0; i < 16; ++i) {
    const int row = i * 4 + wave;
    float4 sv = *(const float4*)(s1b + row * D_DIM + lane * 4);
    float r = RN1[row];
    float x0 = sv.x * k0 * r, x1 = sv.y * k1 * r, x2 = sv.z * k2 * r, x3 = sv.w * k3 * r;
    unsigned int p0 = ((unsigned int)f2bf(x1) << 16) | f2bf(x0);
    unsigned int p1 = ((unsigned int)f2bf(x3) << 16) | f2bf(x2);
    *(uint2*)&X1[row * LDX + lane * 4] = make_uint2(p0, p1);
  }

  float rmax0 = -1e30f, rmax1 = -1e30f;
  const unsigned short* s2b = s2bf + (size_t)b * L_DIM * D_DIM;

  // A-fragment swizzled bases: row rA0 = wm*32+lr (xor key lr), rA1 = +16 (key lr^16)
  const int baseA0 = (wm * 32 + lr) * 256;
  const int baseA1 = baseA0 + 16 * 256;
  const unsigned short* b0p = &X1[(wl * 32 + lr) * LDX + q * 8];
  const unsigned short* b1p = &X1[(wl * 32 + 16 + lr) * LDX + q * 8];

  for (int mt = 0; mt < L_DIM / TM; ++mt) {
    if (mt) __syncthreads();   // prior MFMA's X2 reads complete before overwrite
    // async stage X2 (32KB): granule s=j*256+tid holds global chunk (x ^ (r&31)) of row r
    {
      const unsigned short* srcb = s2b + mt * TM * 256;
      unsigned short* ldsb = &X2[wave * 64 * 8];          // wave-uniform base
      #pragma unroll
      for (int j = 0; j < 8; ++j) {
        int sg = j * 256 + tid;
        int r  = sg >> 5, x = sg & 31;
        int c  = x ^ (r & 31);
        const unsigned short* g = srcb + r * 256 + c * 8;
        __builtin_amdgcn_global_load_lds(
            (const __attribute__((address_space(1))) void*)g,
            (__attribute__((address_space(3))) void*)(ldsb + j * 256 * 8),
            16, 0, 0);
      }
    }
    __syncthreads();   // vmcnt drained by barrier; X1 also visible (mt=0)

    f32x4 acc00 = {0,0,0,0}, acc01 = {0,0,0,0}, acc10 = {0,0,0,0}, acc11 = {0,0,0,0};
    #pragma unroll
    for (int kt = 0; kt < 8; ++kt) {
      const int cc = q + kt * 4;
      bf16x8 a0 = *(const bf16x8*)&X2[baseA0 + ((cc ^ lr) << 3)];
      bf16x8 a1 = *(const bf16x8*)&X2[baseA1 + ((cc ^ lr ^ 16) << 3)];
      bf16x8 b0 = *(const bf16x8*)(b0p + kt * 32);
      bf16x8 b1 = *(const bf16x8*)(b1p + kt * 32);
      acc00 = __builtin_amdgcn_mfma_f32_16x16x32_bf16(a0, b0, acc00, 0, 0, 0);
      acc01 = __builtin_amdgcn_mfma_f32_16x16x32_bf16(a0, b1, acc01, 0, 0, 0);
      acc10 = __builtin_amdgcn_mfma_f32_16x16x32_bf16(a1, b0, acc10, 0, 0, 0);
      acc11 = __builtin_amdgcn_mfma_f32_16x16x32_bf16(a1, b1, acc11, 0, 0, 0);
    }

    // epilogue: rn1 already folded into X1; apply rn2, fold max over m
    #pragma unroll
    for (int r = 0; r < 4; ++r) {
      float rm0 = RN2[mt * TM + wm * 32 + q * 4 + r];
      float rm1 = RN2[mt * TM + wm * 32 + 16 + q * 4 + r];
      rmax0 = fmaxf(rmax0, fmaxf(acc00[r] * rm0, acc10[r] * rm1));
      rmax1 = fmaxf(rmax1, fmaxf(acc01[r] * rm0, acc11[r] * rm1));
    }
  }

  // cross-quad max (each lane holds max over its own m rows)
  rmax0 = fmaxf(rmax0, __shfl_xor(rmax0, 16));
  rmax0 = fmaxf(rmax0, __shfl_xor(rmax0, 32));
  rmax1 = fmaxf(rmax1, __shfl_xor(rmax1, 16));
  rmax1 = fmaxf(rmax1, __shfl_xor(rmax1, 32));
  if (q == 0) {
    outtmp[wm][wl * 32 + lr]      = rmax0;
    outtmp[wm][wl * 32 + 16 + lr] = rmax1;
  }
  __syncthreads();
  if (tid < TL)
    outg[((size_t)b * L_DIM + (l0 + tid)) * P_DIM + p] =
        fmaxf(outtmp[0][tid], outtmp[1][tid]);
}

extern "C" void kernel_launch(void* const* d_in, const int* in_sizes, int n_in,
                              void* d_out, int out_size, void* d_ws, size_t ws_size,
                              hipStream_t stream) {
  const float* s1 = (const float*)d_in[0];
  const float* s2 = (const float*)d_in[1];
  const float* kg = (const float*)d_in[2];
  float* out = (float*)d_out;

  // workspace: rn1 [B*P*L] f32 | rn2 [B*P*L] f32 | s2bf [B*L*D] bf16  (~2.75 MB)
  float* rn1 = (float*)d_ws;
  float* rn2 = rn1 + (size_t)B_DIM * P_DIM * L_DIM;
  unsigned short* s2bf = (unsigned short*)(rn2 + (size_t)B_DIM * P_DIM * L_DIM);

  prep_kernel<<<dim3(2048), dim3(256), 0, stream>>>(s1, s2, kg, rn1, rn2, s2bf);
  mpm_main<<<dim3(B_DIM * P_DIM * (L_DIM / TL)), dim3(256), 0, stream>>>(
      s1, s2bf, kg, rn1, rn2, out);
}

// Round 3
// 96.064 us; speedup vs baseline: 1.8842x; 1.0096x over previous
//
#include <hip/hip_runtime.h>
#include <hip/hip_bf16.h>

// MaxPoolingMatching: out[b,l,p] = max_m cos( s1[b,l,:]∘k[p,:], s2[b,m,:]∘k[p,:] )
// B=16, L=256, D=256, P=20.
//
// v3: one block per (b, l-tile64, p-group-of-5). X2 = bf16(s2) staged ONCE, fully
// resident (256 m rows, 128KB, XOR-swizzled 16B granules). X1 = bf16(s1·k²·rn1)
// rebuilt per p from a 64-VGPR register cache of s1 (32KB, XOR-swizzled).
// Wave tiles 64l×64m (4×4 of 16x16x32 bf16 MFMA) halve LDS-read bytes/MAC vs v2.
// Epilogue: m is reg-indexed in C → in-lane max, ×rn2 via float4 loads, cross-quad
// shfl, cross-wave via 1KB exchange aliased into the (dead) X1 region.
// LDS = 131072 + 32768 = 163840 B exactly (gfx950 GROUP segment max).

#define B_DIM 16
#define L_DIM 256
#define D_DIM 256
#define P_DIM 20
#define EPS 1e-12f

typedef __attribute__((ext_vector_type(8))) __bf16 bf16x8;
typedef __attribute__((ext_vector_type(4))) float f32x4;

__device__ __forceinline__ unsigned short f2bf(float x) {
  unsigned int u = __float_as_uint(x);
  u += 0x7fffu + ((u >> 16) & 1u);   // RNE
  return (unsigned short)(u >> 16);
}

// ---------------- prep: reciprocal norms + bf16(s2) (validated in v2) ----------------
__global__ __launch_bounds__(256)
void prep_kernel(const float* __restrict__ s1, const float* __restrict__ s2,
                 const float* __restrict__ kg, float* __restrict__ rn1,
                 float* __restrict__ rn2, unsigned short* __restrict__ s2bf) {
  const int lane = threadIdx.x & 63;
  const int gw   = blockIdx.x * 4 + (threadIdx.x >> 6);   // 0..8191
  const int sent = gw >> 12;                               // 0: s1, 1: s2
  const int row  = gw & 4095;                              // b*256 + l
  const float* src = sent ? s2 : s1;
  float4 sv = *(const float4*)(src + (size_t)row * D_DIM + lane * 4);
  if (sent) {
    unsigned int p0 = ((unsigned int)f2bf(sv.y) << 16) | f2bf(sv.x);
    unsigned int p1 = ((unsigned int)f2bf(sv.w) << 16) | f2bf(sv.z);
    *(uint2*)&s2bf[(size_t)row * D_DIM + lane * 4] = make_uint2(p0, p1);
  }
  float q0 = sv.x * sv.x, q1 = sv.y * sv.y, q2 = sv.z * sv.z, q3 = sv.w * sv.w;
  float* rn = sent ? rn2 : rn1;
  const int b = row >> 8, l = row & 255;
  #pragma unroll 4
  for (int p = 0; p < P_DIM; ++p) {
    float4 kv = *(const float4*)(kg + p * D_DIM + lane * 4);
    float v = q0 * kv.x * kv.x + q1 * kv.y * kv.y + q2 * kv.z * kv.z + q3 * kv.w * kv.w;
    #pragma unroll
    for (int off = 1; off < 64; off <<= 1) v += __shfl_xor(v, off);
    if (lane == 0) rn[((size_t)b * P_DIM + p) * L_DIM + l] = rsqrtf(fmaxf(v, EPS));
  }
}

// ---------------- main ----------------
__global__ __launch_bounds__(256, 1)
void mpm_main(const float* __restrict__ s1, const unsigned short* __restrict__ s2bf,
              const float* __restrict__ kg, const float* __restrict__ rn1,
              const float* __restrict__ rn2, float* __restrict__ outg) {
  __shared__ __align__(16) unsigned short X2[256 * 256];  // 128KB, all 256 m rows
  __shared__ __align__(16) unsigned short X1[64 * 256];   // 32KB, 64 l rows
  float* WoutF = (float*)X1;                              // 1KB alias, used when X1 dead

  const int tid  = threadIdx.x;
  const int lane = tid & 63;
  const int wave = tid >> 6;       // 0..3 = m-quarter (64 m rows each)
  const int lr   = lane & 15;
  const int q    = lane >> 4;

  const int bid = blockIdx.x;      // 256 blocks = b(16) x lt(4) x pgi(4)
  const int pgi = bid & 3;
  const int lt  = (bid >> 2) & 3;
  const int b   = bid >> 4;
  const int l0  = lt * 64;

  // ---- stage X2 once: 8192 granules of 16B, swizzled: phys granule (r, pr) holds
  // logical column chunk c = pr ^ (r&31) of row r ----
  {
    const unsigned short* s2b = s2bf + (size_t)b * L_DIM * D_DIM;
    #pragma unroll
    for (int j = 0; j < 32; ++j) {
      int g = j * 256 + tid;                 // dst = base(j,wave) + lane*16B : wave-uniform OK
      int r = g >> 5, pr = g & 31;
      int c = pr ^ (r & 31);
      __builtin_amdgcn_global_load_lds(
          (const __attribute__((address_space(1))) void*)(s2b + r * 256 + c * 8),
          (__attribute__((address_space(3))) void*)(X2 + (size_t)g * 8),
          16, 0, 0);
    }
  }

  // ---- cache raw s1 tile in registers: 16 rows/wave-lane x float4 = 64 VGPRs ----
  float4 s1r[16];
  {
    const float* s1b = s1 + ((size_t)b * L_DIM + l0) * D_DIM;
    #pragma unroll
    for (int i = 0; i < 16; ++i)
      s1r[i] = *(const float4*)(s1b + (i * 4 + wave) * D_DIM + lane * 4);
  }

  // precompute MFMA row indices / swizzle keys
  int mrow[4], mkey[4];
  #pragma unroll
  for (int mi = 0; mi < 4; ++mi) {
    mrow[mi] = wave * 64 + mi * 16 + lr;
    mkey[mi] = mrow[mi] & 31;
  }

  #pragma unroll 1
  for (int pp = 0; pp < 5; ++pp) {
    const int p = pgi * 5 + pp;
    __syncthreads();   // drains X2 staging (pp=0); protects WoutF reads (pp>0)

    // ---- build X1 = bf16(s1 * k^2 * rn1) , swizzled ----
    {
      float4 kv = *(const float4*)(kg + p * D_DIM + lane * 4);
      const float k0 = kv.x * kv.x, k1 = kv.y * kv.y, k2 = kv.z * kv.z, k3 = kv.w * kv.w;
      const float* rn1b = rn1 + ((size_t)b * P_DIM + p) * L_DIM + l0;
      #pragma unroll
      for (int i = 0; i < 16; ++i) {
        const int row = i * 4 + wave;
        const float rv = rn1b[row];
        float x0 = s1r[i].x * k0 * rv, x1 = s1r[i].y * k1 * rv;
        float x2 = s1r[i].z * k2 * rv, x3 = s1r[i].w * k3 * rv;
        unsigned int p0 = ((unsigned int)f2bf(x1) << 16) | f2bf(x0);
        unsigned int p1 = ((unsigned int)f2bf(x3) << 16) | f2bf(x2);
        // 8B store: granule (lane>>1)^(row&31), half (lane&1)
        *(uint2*)&X1[row * 256 + (((lane >> 1) ^ (row & 31)) << 3) + ((lane & 1) << 2)] =
            make_uint2(p0, p1);
      }
    }
    __syncthreads();   // X1 visible

    // ---- K-loop: wave computes C[64m x 64l] = X2-rows · X1-rows^T ----
    f32x4 acc[4][4];
    #pragma unroll
    for (int mi = 0; mi < 4; ++mi)
      #pragma unroll
      for (int li = 0; li < 4; ++li) acc[mi][li] = (f32x4){0.f, 0.f, 0.f, 0.f};

    #pragma unroll
    for (int kstep = 0; kstep < 8; ++kstep) {
      const int cc = kstep * 4 + q;
      bf16x8 a[4], bb[4];
      #pragma unroll
      for (int mi = 0; mi < 4; ++mi)
        a[mi] = *(const bf16x8*)&X2[mrow[mi] * 256 + ((cc ^ mkey[mi]) << 3)];
      #pragma unroll
      for (int li = 0; li < 4; ++li) {
        const int l = li * 16 + lr;
        bb[li] = *(const bf16x8*)&X1[l * 256 + ((cc ^ (l & 31)) << 3)];
      }
      #pragma unroll
      for (int mi = 0; mi < 4; ++mi)
        #pragma unroll
        for (int li = 0; li < 4; ++li)
          acc[mi][li] = __builtin_amdgcn_mfma_f32_16x16x32_bf16(a[mi], bb[li], acc[mi][li], 0, 0, 0);
    }

    // ---- epilogue: C row = m (= q*4+reg + mi*16 + wave*64), col = l (= lane&15 + li*16)
    float4 r2[4];
    {
      const float* rn2b = rn2 + ((size_t)b * P_DIM + p) * L_DIM + wave * 64;
      #pragma unroll
      for (int mi = 0; mi < 4; ++mi)
        r2[mi] = *(const float4*)(rn2b + mi * 16 + q * 4);   // rn2 for m = base+q*4+{0..3}
    }
    float v[4];
    #pragma unroll
    for (int li = 0; li < 4; ++li) {
      float t = -3.4e38f;
      #pragma unroll
      for (int mi = 0; mi < 4; ++mi) {
        t = fmaxf(t, acc[mi][li][0] * r2[mi].x);
        t = fmaxf(t, acc[mi][li][1] * r2[mi].y);
        t = fmaxf(t, acc[mi][li][2] * r2[mi].z);
        t = fmaxf(t, acc[mi][li][3] * r2[mi].w);
      }
      t = fmaxf(t, __shfl_xor(t, 16));   // combine quads (different m subsets, same l)
      t = fmaxf(t, __shfl_xor(t, 32));
      v[li] = t;
    }

    __syncthreads();   // all waves done reading X1 region -> safe to alias as WoutF
    if (q == 0) {
      #pragma unroll
      for (int li = 0; li < 4; ++li) WoutF[wave * 64 + li * 16 + lr] = v[li];
    }
    __syncthreads();
    if (tid < 64) {
      float o = fmaxf(fmaxf(WoutF[tid], WoutF[64 + tid]),
                      fmaxf(WoutF[128 + tid], WoutF[192 + tid]));
      outg[((size_t)b * L_DIM + (l0 + tid)) * P_DIM + p] = o;
    }
  }
}

extern "C" void kernel_launch(void* const* d_in, const int* in_sizes, int n_in,
                              void* d_out, int out_size, void* d_ws, size_t ws_size,
                              hipStream_t stream) {
  const float* s1 = (const float*)d_in[0];
  const float* s2 = (const float*)d_in[1];
  const float* kg = (const float*)d_in[2];
  float* out = (float*)d_out;

  // workspace: rn1 [B*P*L] f32 | rn2 [B*P*L] f32 | s2bf [B*L*D] bf16  (~2.75 MB)
  float* rn1 = (float*)d_ws;
  float* rn2 = rn1 + (size_t)B_DIM * P_DIM * L_DIM;
  unsigned short* s2bf = (unsigned short*)(rn2 + (size_t)B_DIM * P_DIM * L_DIM);

  prep_kernel<<<dim3(2048), dim3(256), 0, stream>>>(s1, s2, kg, rn1, rn2, s2bf);
  mpm_main<<<dim3(256), dim3(256), 0, stream>>>(s1, s2bf, kg, rn1, rn2, out);
}

// Round 4
// 82.601 us; speedup vs baseline: 2.1913x; 1.1630x over previous
//
#include <hip/hip_runtime.h>
#include <hip/hip_bf16.h>

// MaxPoolingMatching: out[b,l,p] = max_m cos( s1[b,l,:]∘k[p,:], s2[b,m,:]∘k[p,:] )
// B=16, L=256, D=256, P=20.
//
// v4: prep is now MFMA-based (no shfl reduce chains — they were ~25µs of serialized
// ds_bpermute): norms rn = rsqrt(max(Σ s²k², EPS)) computed as [rows×256]·[256×20]
// GEMM with A=bf16(s²), B=bf16(k²) in +8-padded LDS tiles; also emits bf16(s1),
// bf16(s2). Main: one block per (b, l-tile64, p-group5), X2=bf16(s2) fully resident
// (128KB, XOR-swizzled), X1=bf16(s1·k²·rn1) rebuilt per p from a register cache of
// bf16(s1); NOW 512 threads (8 waves = 2/SIMD for latency hiding), wave tile 32m×64l.
// LDS main = 131072+32768 = 163840 B exactly.

#define B_DIM 16
#define L_DIM 256
#define D_DIM 256
#define P_DIM 20
#define EPS 1e-12f
#define LDP 264   // padded stride: 2-way bank aliasing only (free)

typedef __attribute__((ext_vector_type(8))) __bf16 bf16x8;
typedef __attribute__((ext_vector_type(4))) float f32x4;

__device__ __forceinline__ unsigned short f2bf(float x) {
  unsigned int u = __float_as_uint(x);
  u += 0x7fffu + ((u >> 16) & 1u);   // RNE
  return (unsigned short)(u >> 16);
}

// ---------------- prep2: MFMA norms + bf16 casts ----------------
// 256 blocks x 256 threads; block = (sentence = bid&1, 32-row tile = bid>>1)
__global__ __launch_bounds__(256)
void prep2(const float* __restrict__ s1, const float* __restrict__ s2,
           const float* __restrict__ kg,
           float* __restrict__ rn1, float* __restrict__ rn2,
           unsigned short* __restrict__ s1bf, unsigned short* __restrict__ s2bf) {
  __shared__ __align__(16) unsigned short QA[32 * LDP];  // bf16(s²) rows
  __shared__ __align__(16) unsigned short QB[32 * LDP];  // bf16(k²) rows (20 valid)
  const int tid = threadIdx.x, lane = tid & 63, wave = tid >> 6;
  const int lr = lane & 15, q = lane >> 4;
  const int sent = blockIdx.x & 1, t = blockIdx.x >> 1;   // t: 0..127
  const int r0 = t * 32, b = r0 >> 8;                     // 32 | 256 -> single b
  const float* src = sent ? s2 : s1;
  unsigned short* sbf = sent ? s2bf : s1bf;
  float* rn = sent ? rn2 : rn1;

  #pragma unroll
  for (int i = 0; i < 8; ++i) {
    const int row = i * 4 + wave;
    float4 sv = *(const float4*)(src + (size_t)(r0 + row) * D_DIM + lane * 4);
    unsigned int c0 = ((unsigned int)f2bf(sv.y) << 16) | f2bf(sv.x);
    unsigned int c1 = ((unsigned int)f2bf(sv.w) << 16) | f2bf(sv.z);
    *(uint2*)&sbf[(size_t)(r0 + row) * D_DIM + lane * 4] = make_uint2(c0, c1);
    unsigned int q0 = ((unsigned int)f2bf(sv.y * sv.y) << 16) | f2bf(sv.x * sv.x);
    unsigned int q1 = ((unsigned int)f2bf(sv.w * sv.w) << 16) | f2bf(sv.z * sv.z);
    *(uint2*)&QA[row * LDP + lane * 4] = make_uint2(q0, q1);
  }
  #pragma unroll
  for (int j = 0; j < 5; ++j) {
    const int row = wave * 5 + j;   // 0..19; rows 20..31 of QB stay garbage (masked)
    float4 kv = *(const float4*)(kg + row * D_DIM + lane * 4);
    unsigned int c0 = ((unsigned int)f2bf(kv.y * kv.y) << 16) | f2bf(kv.x * kv.x);
    unsigned int c1 = ((unsigned int)f2bf(kv.w * kv.w) << 16) | f2bf(kv.z * kv.z);
    *(uint2*)&QB[row * LDP + lane * 4] = make_uint2(c0, c1);
  }
  __syncthreads();

  // wave w: m-tile (w&1) of the 32 rows, n-tile (w>>1) of p∈[0,32)
  const int mt = wave & 1, nt = wave >> 1;
  f32x4 acc = {0.f, 0.f, 0.f, 0.f};
  #pragma unroll
  for (int ks = 0; ks < 8; ++ks) {
    const int cc = ks * 4 + q;
    bf16x8 a  = *(const bf16x8*)&QA[(mt * 16 + lr) * LDP + cc * 8];
    bf16x8 bb = *(const bf16x8*)&QB[(nt * 16 + lr) * LDP + cc * 8];
    acc = __builtin_amdgcn_mfma_f32_16x16x32_bf16(a, bb, acc, 0, 0, 0);
  }
  // C: row(reg) = sentence-row, col(lane) = p
  const int p = nt * 16 + lr;
  if (p < P_DIM) {
    #pragma unroll
    for (int r = 0; r < 4; ++r) {
      const int l = (r0 & 255) + mt * 16 + q * 4 + r;
      rn[((size_t)b * P_DIM + p) * L_DIM + l] = rsqrtf(fmaxf(acc[r], EPS));
    }
  }
}

// ---------------- main ----------------
__global__ __launch_bounds__(512, 1)
void mpm_main(const unsigned short* __restrict__ s1bf,
              const unsigned short* __restrict__ s2bf,
              const float* __restrict__ kg, const float* __restrict__ rn1,
              const float* __restrict__ rn2, float* __restrict__ outg) {
  __shared__ __align__(16) unsigned short X2[256 * 256];  // 128KB, all 256 m rows
  __shared__ __align__(16) unsigned short X1[64 * 256];   // 32KB, 64 l rows
  float* WoutF = (float*)X1;                              // 2KB alias when X1 dead

  const int tid = threadIdx.x, lane = tid & 63, wave = tid >> 6;  // 8 waves
  const int lr = lane & 15, q = lane >> 4;
  const int bid = blockIdx.x;      // 256 = b(16) x lt(4) x pgi(4)
  const int pgi = bid & 3, lt = (bid >> 2) & 3, b = bid >> 4;
  const int l0 = lt * 64;

  // stage X2 once: swizzled — phys granule (r,pr) holds logical chunk pr^(r&31)
  {
    const unsigned short* s2b = s2bf + (size_t)b * L_DIM * D_DIM;
    #pragma unroll
    for (int j = 0; j < 16; ++j) {
      int g = j * 512 + tid;
      int r = g >> 5, pr = g & 31;
      int c = pr ^ (r & 31);
      __builtin_amdgcn_global_load_lds(
          (const __attribute__((address_space(1))) void*)(s2b + r * 256 + c * 8),
          (__attribute__((address_space(3))) void*)(X2 + (size_t)g * 8), 16, 0, 0);
    }
  }

  // register-cache bf16(s1) tile: 8 rows per wave, 8B/lane
  uint2 s1r[8];
  {
    const unsigned short* s1b = s1bf + ((size_t)b * L_DIM + l0) * D_DIM;
    #pragma unroll
    for (int i = 0; i < 8; ++i)
      s1r[i] = *(const uint2*)(s1b + (size_t)(i * 8 + wave) * D_DIM + lane * 4);
  }

  const int mrow0 = wave * 32 + lr,  mrow1 = wave * 32 + 16 + lr;
  const int mkey0 = mrow0 & 31,      mkey1 = mrow1 & 31;

  #pragma unroll 1
  for (int pp = 0; pp < 5; ++pp) {
    const int p = pgi * 5 + pp;
    __syncthreads();   // pp=0: staging drained; pp>0: WoutF consumed, X1 reads done

    // build X1 = bf16( s1 * k^2 * rn1 ), swizzled 8B stores
    {
      float4 kv = *(const float4*)(kg + p * D_DIM + lane * 4);
      const float k0 = kv.x * kv.x, k1 = kv.y * kv.y, k2 = kv.z * kv.z, k3 = kv.w * kv.w;
      const float* rn1b = rn1 + ((size_t)b * P_DIM + p) * L_DIM + l0;
      #pragma unroll
      for (int i = 0; i < 8; ++i) {
        const int row = i * 8 + wave;
        const float rv = rn1b[row];          // wave-uniform -> s_load
        float x0 = __uint_as_float(s1r[i].x << 16)          * k0 * rv;
        float x1 = __uint_as_float(s1r[i].x & 0xffff0000u)  * k1 * rv;
        float x2 = __uint_as_float(s1r[i].y << 16)          * k2 * rv;
        float x3 = __uint_as_float(s1r[i].y & 0xffff0000u)  * k3 * rv;
        unsigned int c0 = ((unsigned int)f2bf(x1) << 16) | f2bf(x0);
        unsigned int c1 = ((unsigned int)f2bf(x3) << 16) | f2bf(x2);
        *(uint2*)&X1[row * 256 + (((lane >> 1) ^ (row & 31)) << 3) + ((lane & 1) << 2)] =
            make_uint2(c0, c1);
      }
    }
    __syncthreads();   // X1 visible

    // K-loop: wave computes C[32m x 64l]
    f32x4 acc[2][4];
    #pragma unroll
    for (int mi = 0; mi < 2; ++mi)
      #pragma unroll
      for (int li = 0; li < 4; ++li) acc[mi][li] = (f32x4){0.f, 0.f, 0.f, 0.f};

    #pragma unroll
    for (int ks = 0; ks < 8; ++ks) {
      const int cc = ks * 4 + q;
      bf16x8 a0 = *(const bf16x8*)&X2[mrow0 * 256 + ((cc ^ mkey0) << 3)];
      bf16x8 a1 = *(const bf16x8*)&X2[mrow1 * 256 + ((cc ^ mkey1) << 3)];
      bf16x8 bb[4];
      #pragma unroll
      for (int li = 0; li < 4; ++li) {
        const int l = li * 16 + lr;
        bb[li] = *(const bf16x8*)&X1[l * 256 + ((cc ^ (l & 31)) << 3)];
      }
      #pragma unroll
      for (int li = 0; li < 4; ++li) {
        acc[0][li] = __builtin_amdgcn_mfma_f32_16x16x32_bf16(a0, bb[li], acc[0][li], 0, 0, 0);
        acc[1][li] = __builtin_amdgcn_mfma_f32_16x16x32_bf16(a1, bb[li], acc[1][li], 0, 0, 0);
      }
    }

    // epilogue: C row(reg) = m = wave*32 + mi*16 + q*4 + r ; col(lane) = l = li*16+lr
    float4 r20, r21;
    {
      const float* rn2b = rn2 + ((size_t)b * P_DIM + p) * L_DIM + wave * 32;
      r20 = *(const float4*)(rn2b + q * 4);
      r21 = *(const float4*)(rn2b + 16 + q * 4);
    }
    float v[4];
    #pragma unroll
    for (int li = 0; li < 4; ++li) {
      float t = -3.4e38f;
      t = fmaxf(t, fmaxf(acc[0][li][0] * r20.x, acc[1][li][0] * r21.x));
      t = fmaxf(t, fmaxf(acc[0][li][1] * r20.y, acc[1][li][1] * r21.y));
      t = fmaxf(t, fmaxf(acc[0][li][2] * r20.z, acc[1][li][2] * r21.z));
      t = fmaxf(t, fmaxf(acc[0][li][3] * r20.w, acc[1][li][3] * r21.w));
      t = fmaxf(t, __shfl_xor(t, 16));
      t = fmaxf(t, __shfl_xor(t, 32));
      v[li] = t;
    }

    __syncthreads();   // X1 reads done -> alias region safe
    if (q == 0) {
      #pragma unroll
      for (int li = 0; li < 4; ++li) WoutF[wave * 64 + li * 16 + lr] = v[li];
    }
    __syncthreads();   // WoutF visible
    if (tid < 64) {
      float o = WoutF[tid];
      #pragma unroll
      for (int w = 1; w < 8; ++w) o = fmaxf(o, WoutF[w * 64 + tid]);
      outg[((size_t)b * L_DIM + (l0 + tid)) * P_DIM + p] = o;
    }
  }
}

extern "C" void kernel_launch(void* const* d_in, const int* in_sizes, int n_in,
                              void* d_out, int out_size, void* d_ws, size_t ws_size,
                              hipStream_t stream) {
  const float* s1 = (const float*)d_in[0];
  const float* s2 = (const float*)d_in[1];
  const float* kg = (const float*)d_in[2];
  float* out = (float*)d_out;

  // ws: rn1 | rn2 (B*P*L f32 each) | s2bf | s1bf (B*L*D bf16 each)  ≈ 9 MB
  float* rn1 = (float*)d_ws;
  float* rn2 = rn1 + (size_t)B_DIM * P_DIM * L_DIM;
  unsigned short* s2bf = (unsigned short*)(rn2 + (size_t)B_DIM * P_DIM * L_DIM);
  unsigned short* s1bf = s2bf + (size_t)B_DIM * L_DIM * D_DIM;

  prep2<<<dim3(256), dim3(256), 0, stream>>>(s1, s2, kg, rn1, rn2, s1bf, s2bf);
  mpm_main<<<dim3(256), dim3(512), 0, stream>>>(s1bf, s2bf, kg, rn1, rn2, out);
}